// Round 11
// baseline (599.379 us; speedup 1.0000x reference)
//
#include <hip/hip_runtime.h>
#include <stdint.h>

typedef __attribute__((ext_vector_type(4))) _Float16 half4;
typedef __attribute__((ext_vector_type(4))) float f32x4;

#define LR 0.1f
#define BLOCK 256
#define MFMA16 __builtin_amdgcn_mfma_f32_16x16x16f16
#define SCHEDB __builtin_amdgcn_sched_barrier

// LDS byte offsets (total 75456 <= 80KB -> 2 blocks/CU)
#define TD_OFF    41472     // td A-frags layers I-1=2..8: 7 x 4608
#define BH_OFF    73728     // bh f32 9*48 = 1728
#define LDS_BYTES 75456

extern __shared__ unsigned char smem[];

// build half4 from 4 floats, RNE scalar casts (SSA vector inserts, no alloca)
#define PACK4(S0,S1,S2,S3) __extension__({ \
  half4 _b; \
  _b[0] = (_Float16)(S0); _b[1] = (_Float16)(S1); \
  _b[2] = (_Float16)(S2); _b[3] = (_Float16)(S3); \
  _b; })

// td A-frag selector: layers 1-2 from registers, 3-9 from LDS (I is a literal)
#define TDA(I, ST) ((I) <= 2 \
  ? tdreg[(I) <= 2 ? (I)-1 : 0][ST] \
  : *(const half4*)(smem + TD_OFF + ((I) >= 3 ? (I)-3 : 0)*4608 + (ST)*512 + lane*8))

// pred-direction 48x48 matvec, f16 2-term split on values (B), bias from bh LDS.
#define PRED48(SRC, WOFF, LIDX, DST) do { \
  f32x4 _a0 = *(const f32x4*)(smem + BH_OFF + ((LIDX)*48 +  0)*4 + b*16); \
  f32x4 _a1 = *(const f32x4*)(smem + BH_OFF + ((LIDX)*48 + 16)*4 + b*16); \
  f32x4 _a2 = *(const f32x4*)(smem + BH_OFF + ((LIDX)*48 + 32)*4 + b*16); \
  _Pragma("unroll") \
  for (int _ks = 0; _ks < 3; ++_ks) { \
    _Float16 _h0 = (_Float16)SRC[_ks*4+0]; \
    _Float16 _h1 = (_Float16)SRC[_ks*4+1]; \
    _Float16 _h2 = (_Float16)SRC[_ks*4+2]; \
    _Float16 _h3 = (_Float16)SRC[_ks*4+3]; \
    half4 _bh; _bh[0]=_h0; _bh[1]=_h1; _bh[2]=_h2; _bh[3]=_h3; \
    half4 _bl; \
    _bl[0] = (_Float16)(SRC[_ks*4+0] - (float)_h0); \
    _bl[1] = (_Float16)(SRC[_ks*4+1] - (float)_h1); \
    _bl[2] = (_Float16)(SRC[_ks*4+2] - (float)_h2); \
    _bl[3] = (_Float16)(SRC[_ks*4+3] - (float)_h3); \
    half4 _A0 = *(const half4*)(smem + (WOFF) + (0*3+_ks)*512 + lane*8); \
    half4 _A1 = *(const half4*)(smem + (WOFF) + (1*3+_ks)*512 + lane*8); \
    half4 _A2 = *(const half4*)(smem + (WOFF) + (2*3+_ks)*512 + lane*8); \
    _a0 = MFMA16(_A0, _bh, _a0, 0, 0, 0); _a0 = MFMA16(_A0, _bl, _a0, 0, 0, 0); \
    _a1 = MFMA16(_A1, _bh, _a1, 0, 0, 0); _a1 = MFMA16(_A1, _bl, _a1, 0, 0, 0); \
    _a2 = MFMA16(_A2, _bh, _a2, 0, 0, 0); _a2 = MFMA16(_A2, _bl, _a2, 0, 0, 0); \
  } \
  _Pragma("unroll") \
  for (int _q = 0; _q < 4; ++_q) { \
    DST[0+_q] = _a0[_q]; DST[4+_q] = _a1[_q]; DST[8+_q] = _a2[_q]; \
  } \
} while(0)

// td-direction 48x48 matvec, single f16 (LR-damped), no bias. I literal.
#define TD48(SRC, I, DST) do { \
  f32x4 _a0 = {0.f,0.f,0.f,0.f}, _a1 = {0.f,0.f,0.f,0.f}, _a2 = {0.f,0.f,0.f,0.f}; \
  _Pragma("unroll") \
  for (int _ks = 0; _ks < 3; ++_ks) { \
    half4 _bb = PACK4(SRC[_ks*4+0], SRC[_ks*4+1], SRC[_ks*4+2], SRC[_ks*4+3]); \
    half4 _A0 = TDA(I, 0*3+_ks); \
    half4 _A1 = TDA(I, 1*3+_ks); \
    half4 _A2 = TDA(I, 2*3+_ks); \
    _a0 = MFMA16(_A0, _bb, _a0, 0, 0, 0); \
    _a1 = MFMA16(_A1, _bb, _a1, 0, 0, 0); \
    _a2 = MFMA16(_A2, _bb, _a2, 0, 0, 0); \
  } \
  _Pragma("unroll") \
  for (int _q = 0; _q < 4; ++_q) { \
    DST[0+_q] = _a0[_q]; DST[4+_q] = _a1[_q]; DST[8+_q] = _a2[_q]; \
  } \
} while(0)

#define LAYER_STEP(I) do { \
  float _pre[12], _err[12], _me[12], _td[12]; \
  PRED48(v[(I)-1], ((I)-1)*4608, (I)-1, _pre); \
  _Pragma("unroll") \
  for (int _q = 0; _q < 12; ++_q) { \
    float _rl = fmaxf(_pre[_q], 0.f); \
    _err[_q] = v[I][_q] - _rl; \
    _me[_q] = (_pre[_q] > 0.f) ? _err[_q] : 0.f; \
  } \
  TD48(_me, I, _td); \
  _Pragma("unroll") \
  for (int _q = 0; _q < 12; ++_q) { \
    float _nv = v[(I)-1][_q] - LR*(ep[_q] - _td[_q]); \
    v[(I)-1][_q] = fminf(fmaxf(_nv, -10.f), 10.f); \
    ep[_q] = _err[_q]; \
  } \
  SCHEDB(0); \
} while(0)

#define FWD(I) do { \
  float _pre[12]; \
  PRED48(v[(I)-1], ((I)-1)*4608, (I)-1, _pre); \
  _Pragma("unroll") \
  for (int _q = 0; _q < 12; ++_q) v[I][_q] = fmaxf(_pre[_q], 0.f); \
  SCHEDB(0); \
} while(0)

__global__ __launch_bounds__(BLOCK) __attribute__((amdgpu_waves_per_eu(1, 2)))
void pcnet_kernel(const float* __restrict__ x, const int* __restrict__ target,
                  const float* __restrict__ W0, const float* __restrict__ b0,
                  const float* __restrict__ Wh, const float* __restrict__ bh,
                  const float* __restrict__ Wout, const float* __restrict__ bout,
                  float* __restrict__ out)
{
    const int t = threadIdx.x;
    const int lane = t & 63;
    const int wv = t >> 6;
    const int n = lane & 15;    // own sample within wave
    const int b = lane >> 4;    // comp sub-block 0..3 (owns comps 16t+4b+q)

    const int bsamp0 = blockIdx.x*64 + wv*16;   // wave's first sample
    const int samp = bsamp0 + n;

    // ======== phase 0: a0 = relu(x@W0^T + b0) via MFMA; x is B-operand ========
    f32x4 acc0[3];
    #pragma unroll
    for (int tm = 0; tm < 3; ++tm) acc0[tm] = (f32x4){0.f, 0.f, 0.f, 0.f};

    const float* xrow = x + (size_t)samp*784;
    for (int ch = 0; ch < 7; ++ch) {
        __syncthreads();
        for (int idx = t; idx < 1344; idx += BLOCK) {
            int st = idx >> 6, LB = idx & 63;
            int tm = st / 7, ksl = st - tm*7;
            int row = 16*tm + (LB & 15);
            int col = ch*112 + ksl*16 + 4*(LB >> 4);
            float4 w4 = *(const float4*)(W0 + row*784 + col);
            *(half4*)(smem + (tm*7+ksl)*512 + LB*8) = PACK4(w4.x, w4.y, w4.z, w4.w);
        }
        __syncthreads();
        #pragma unroll
        for (int ksl = 0; ksl < 7; ++ksl) {
            float4 xv = *(const float4*)(xrow + ch*112 + ksl*16 + 4*b);
            half4 xb = PACK4(xv.x, xv.y, xv.z, xv.w);
            #pragma unroll
            for (int tm = 0; tm < 3; ++tm) {
                half4 A = *(const half4*)(smem + (tm*7+ksl)*512 + lane*8);
                acc0[tm] = MFMA16(A, xb, acc0[tm], 0, 0, 0);
            }
        }
    }

    float v[10][12], a0r[12];
    #pragma unroll
    for (int tm = 0; tm < 3; ++tm) {
        float4 bb = *(const float4*)(b0 + 16*tm + 4*b);
        float bs[4] = {bb.x, bb.y, bb.z, bb.w};
        #pragma unroll
        for (int q = 0; q < 4; ++q) {
            float val = fmaxf(acc0[tm][q] + bs[q], 0.f);
            v[0][tm*4+q] = val;
            a0r[tm*4+q] = val;
        }
    }
    __syncthreads();   // phase-0 reads done before WH staging overwrites

    // ======== stage pred A-frags: 9 layers x 9 subtiles (f16, 8B/lane) ========
    for (int idx = t; idx < 5184; idx += BLOCK) {
        int L = idx / 576;
        int r2 = idx - L*576;
        int st = r2 >> 6, LB = r2 & 63;
        int tm = st / 3, ks = st - tm*3;
        int m  = 16*tm + (LB & 15);
        int k0 = 16*ks + 4*(LB >> 4);
        float4 w4 = *(const float4*)(Wh + L*2304 + m*48 + k0);
        *(half4*)(smem + L*4608 + st*512 + LB*8) = PACK4(w4.x, w4.y, w4.z, w4.w);
    }
    // ======== stage td A-frags: layers 3..9 (Lt=I-3), transposed gather ========
    for (int idx = t; idx < 4032; idx += BLOCK) {
        int Lt = idx / 576;
        int r2 = idx - Lt*576;
        int st = r2 >> 6, LB = r2 & 63;
        int tm = st / 3, ks = st - tm*3;
        int m  = 16*tm + (LB & 15);
        int k0 = 16*ks + 4*(LB >> 4);
        const float* p = Wh + (Lt+2)*2304 + k0*48 + m;
        *(half4*)(smem + TD_OFF + Lt*4608 + st*512 + LB*8) = PACK4(p[0], p[48], p[96], p[144]);
    }
    for (int idx = t; idx < 432; idx += BLOCK)
        *(float*)(smem + BH_OFF + idx*4) = bh[idx];
    __syncthreads();   // last barrier -- settling loop is barrier-free

    // ======== hoist td frags (layers 1-2), output-layer frags, bias ========
    half4 tdreg[2][9];
    #pragma unroll
    for (int L = 0; L < 2; ++L)
        #pragma unroll
        for (int st = 0; st < 9; ++st) {
            int tm = st / 3, ks = st - tm*3;
            int m  = 16*tm + (lane & 15);
            int k0 = 16*ks + 4*(lane >> 4);
            const float* p = Wh + L*2304 + k0*48 + m;
            tdreg[L][st] = PACK4(p[0], p[48], p[96], p[144]);
        }
    half4 WP[3], WT[3];
    {
        int c = lane & 15;
        #pragma unroll
        for (int ks = 0; ks < 3; ++ks) {
            if (c < 10) {
                float4 w4 = *(const float4*)(Wout + c*48 + 16*ks + 4*(lane >> 4));
                WP[ks] = PACK4(w4.x, w4.y, w4.z, w4.w);
            } else {
                WP[ks] = PACK4(0.f, 0.f, 0.f, 0.f);
            }
        }
        int c0 = 4*(lane >> 4);
        #pragma unroll
        for (int tm = 0; tm < 3; ++tm) {
            int m = 16*tm + (lane & 15);
            float w0 = (c0+0 < 10) ? Wout[(c0+0)*48 + m] : 0.f;
            float w1 = (c0+1 < 10) ? Wout[(c0+1)*48 + m] : 0.f;
            float w2 = (c0+2 < 10) ? Wout[(c0+2)*48 + m] : 0.f;
            float w3 = (c0+3 < 10) ? Wout[(c0+3)*48 + m] : 0.f;
            WT[tm] = PACK4(w0, w1, w2, w3);
        }
    }
    f32x4 bo4;
    #pragma unroll
    for (int q = 0; q < 4; ++q) bo4[q] = (4*b+q < 10) ? bout[4*b+q] : 0.f;
    const int tg = target[samp];

    // ======== forward init layers 1..9 ========
    FWD(1); FWD(2); FWD(3); FWD(4); FWD(5); FWD(6); FWD(7); FWD(8); FWD(9);

    // ======== settling ========
    #pragma unroll 1
    for (int s = 0; s < 20; ++s) {
        float ep[12];
        #pragma unroll
        for (int q = 0; q < 12; ++q) ep[q] = v[0][q] - a0r[q];

        LAYER_STEP(1); LAYER_STEP(2); LAYER_STEP(3); LAYER_STEP(4); LAYER_STEP(5);
        LAYER_STEP(6); LAYER_STEP(7); LAYER_STEP(8); LAYER_STEP(9);

        // ---- output layer (single f16: LR-damped), fully lane-local ----
        {
            half4 B9[3];
            #pragma unroll
            for (int ks = 0; ks < 3; ++ks)
                B9[ks] = PACK4(v[9][ks*4+0], v[9][ks*4+1], v[9][ks*4+2], v[9][ks*4+3]);
            f32x4 accP = bo4;
            #pragma unroll
            for (int ks = 0; ks < 3; ++ks)
                accP = MFMA16(WP[ks], B9[ks], accP, 0, 0, 0);
            int c0 = 4*b;
            float e0 = (c0+0 < 10) ? (((c0+0 == tg) ? 1.f : 0.f) - accP[0]) : 0.f;
            float e1 = (c0+1 < 10) ? (((c0+1 == tg) ? 1.f : 0.f) - accP[1]) : 0.f;
            float e2 = (c0+2 < 10) ? (((c0+2 == tg) ? 1.f : 0.f) - accP[2]) : 0.f;
            float e3 = (c0+3 < 10) ? (((c0+3 == tg) ? 1.f : 0.f) - accP[3]) : 0.f;
            half4 eB = PACK4(e0, e1, e2, e3);   // B[k=class 4b+j][own sample]
            float td10[12];
            #pragma unroll
            for (int tm = 0; tm < 3; ++tm) {
                f32x4 a2 = {0.f, 0.f, 0.f, 0.f};
                a2 = MFMA16(WT[tm], eB, a2, 0, 0, 0);
                #pragma unroll
                for (int q = 0; q < 4; ++q) td10[tm*4+q] = a2[q];
            }
            #pragma unroll
            for (int q = 0; q < 12; ++q) {
                float nv = v[9][q] - LR*(ep[q] - td10[q]);
                v[9][q] = fminf(fmaxf(nv, -10.f), 10.f);
            }
            SCHEDB(0);
        }
    }

    // ======== write V: out[L][sample][comp], comps 16t+4b..+3 contiguous ========
    #pragma unroll
    for (int L2 = 0; L2 < 10; ++L2) {
        #pragma unroll
        for (int tt = 0; tt < 3; ++tt) {
            f32x4 w4 = { v[L2][tt*4+0], v[L2][tt*4+1], v[L2][tt*4+2], v[L2][tt*4+3] };
            *(f32x4*)(out + (size_t)L2*65536*48 + (size_t)samp*48 + tt*16 + 4*b) = w4;
        }
    }
}

extern "C" void kernel_launch(void* const* d_in, const int* in_sizes, int n_in,
                              void* d_out, int out_size, void* d_ws, size_t ws_size,
                              hipStream_t stream) {
    const float* x      = (const float*)d_in[0];
    const int*   target = (const int*)d_in[1];
    const float* W0     = (const float*)d_in[2];
    const float* b0     = (const float*)d_in[3];
    const float* Wh     = (const float*)d_in[4];
    const float* bh     = (const float*)d_in[5];
    const float* Wout   = (const float*)d_in[6];
    const float* bout   = (const float*)d_in[7];
    float* out = (float*)d_out;

    hipFuncSetAttribute((const void*)pcnet_kernel,
                        hipFuncAttributeMaxDynamicSharedMemorySize, LDS_BYTES);

    dim3 grid(65536/64);    // 1024 blocks, 64 samples each
    dim3 block(BLOCK);      // 4 waves x 16 samples; 75456 B LDS -> 2 blocks/CU
    pcnet_kernel<<<grid, block, LDS_BYTES, stream>>>(x, target, W0, b0, Wh, bh, Wout, bout, out);
}

// Round 12
// 589.816 us; speedup vs baseline: 1.0162x; 1.0162x over previous
//
#include <hip/hip_runtime.h>
#include <stdint.h>

typedef __attribute__((ext_vector_type(4))) _Float16 half4;
typedef __attribute__((ext_vector_type(4))) float f32x4;

#define LR 0.1f
#define BLOCK 256
#define MFMA16 __builtin_amdgcn_mfma_f32_16x16x16f16
#define SCHEDB __builtin_amdgcn_sched_barrier

// LDS byte offsets (total 61632 <= 64KB -> target 2 blocks/CU)
#define TD_OFF    41472     // td A-frags layers I=6..9: 4 x 4608
#define BH_OFF    59904     // bh f32 9*48 = 1728
#define LDS_BYTES 61632

extern __shared__ unsigned char smem[];

// build half4 from 4 floats, RNE scalar casts (SSA vector inserts, no alloca)
#define PACK4(S0,S1,S2,S3) __extension__({ \
  half4 _b; \
  _b[0] = (_Float16)(S0); _b[1] = (_Float16)(S1); \
  _b[2] = (_Float16)(S2); _b[3] = (_Float16)(S3); \
  _b; })

// td A-frag selector: layers 1-5 from registers, 6-9 from LDS (I is a literal)
#define TDA(I, ST) ((I) <= 5 \
  ? tdreg[(I) <= 5 ? (I)-1 : 0][ST] \
  : *(const half4*)(smem + TD_OFF + ((I) >= 6 ? (I)-6 : 0)*4608 + (ST)*512 + lane*8))

// pred-direction 48x48 matvec, f16 2-term split on values (B), bias from bh LDS.
#define PRED48(SRC, WOFF, LIDX, DST) do { \
  f32x4 _a0 = *(const f32x4*)(smem + BH_OFF + ((LIDX)*48 +  0)*4 + b*16); \
  f32x4 _a1 = *(const f32x4*)(smem + BH_OFF + ((LIDX)*48 + 16)*4 + b*16); \
  f32x4 _a2 = *(const f32x4*)(smem + BH_OFF + ((LIDX)*48 + 32)*4 + b*16); \
  _Pragma("unroll") \
  for (int _ks = 0; _ks < 3; ++_ks) { \
    _Float16 _h0 = (_Float16)SRC[_ks*4+0]; \
    _Float16 _h1 = (_Float16)SRC[_ks*4+1]; \
    _Float16 _h2 = (_Float16)SRC[_ks*4+2]; \
    _Float16 _h3 = (_Float16)SRC[_ks*4+3]; \
    half4 _bh; _bh[0]=_h0; _bh[1]=_h1; _bh[2]=_h2; _bh[3]=_h3; \
    half4 _bl; \
    _bl[0] = (_Float16)(SRC[_ks*4+0] - (float)_h0); \
    _bl[1] = (_Float16)(SRC[_ks*4+1] - (float)_h1); \
    _bl[2] = (_Float16)(SRC[_ks*4+2] - (float)_h2); \
    _bl[3] = (_Float16)(SRC[_ks*4+3] - (float)_h3); \
    half4 _A0 = *(const half4*)(smem + (WOFF) + (0*3+_ks)*512 + lane*8); \
    half4 _A1 = *(const half4*)(smem + (WOFF) + (1*3+_ks)*512 + lane*8); \
    half4 _A2 = *(const half4*)(smem + (WOFF) + (2*3+_ks)*512 + lane*8); \
    _a0 = MFMA16(_A0, _bh, _a0, 0, 0, 0); _a0 = MFMA16(_A0, _bl, _a0, 0, 0, 0); \
    _a1 = MFMA16(_A1, _bh, _a1, 0, 0, 0); _a1 = MFMA16(_A1, _bl, _a1, 0, 0, 0); \
    _a2 = MFMA16(_A2, _bh, _a2, 0, 0, 0); _a2 = MFMA16(_A2, _bl, _a2, 0, 0, 0); \
  } \
  _Pragma("unroll") \
  for (int _q = 0; _q < 4; ++_q) { \
    DST[0+_q] = _a0[_q]; DST[4+_q] = _a1[_q]; DST[8+_q] = _a2[_q]; \
  } \
} while(0)

// td-direction 48x48 matvec, single f16 (LR-damped), no bias. I literal.
#define TD48(SRC, I, DST) do { \
  f32x4 _a0 = {0.f,0.f,0.f,0.f}, _a1 = {0.f,0.f,0.f,0.f}, _a2 = {0.f,0.f,0.f,0.f}; \
  _Pragma("unroll") \
  for (int _ks = 0; _ks < 3; ++_ks) { \
    half4 _bb = PACK4(SRC[_ks*4+0], SRC[_ks*4+1], SRC[_ks*4+2], SRC[_ks*4+3]); \
    half4 _A0 = TDA(I, 0*3+_ks); \
    half4 _A1 = TDA(I, 1*3+_ks); \
    half4 _A2 = TDA(I, 2*3+_ks); \
    _a0 = MFMA16(_A0, _bb, _a0, 0, 0, 0); \
    _a1 = MFMA16(_A1, _bb, _a1, 0, 0, 0); \
    _a2 = MFMA16(_A2, _bb, _a2, 0, 0, 0); \
  } \
  _Pragma("unroll") \
  for (int _q = 0; _q < 4; ++_q) { \
    DST[0+_q] = _a0[_q]; DST[4+_q] = _a1[_q]; DST[8+_q] = _a2[_q]; \
  } \
} while(0)

#define LAYER_STEP(I) do { \
  float _pre[12], _err[12], _me[12], _td[12]; \
  PRED48(v[(I)-1], ((I)-1)*4608, (I)-1, _pre); \
  _Pragma("unroll") \
  for (int _q = 0; _q < 12; ++_q) { \
    float _rl = fmaxf(_pre[_q], 0.f); \
    _err[_q] = v[I][_q] - _rl; \
    _me[_q] = (_pre[_q] > 0.f) ? _err[_q] : 0.f; \
  } \
  TD48(_me, I, _td); \
  _Pragma("unroll") \
  for (int _q = 0; _q < 12; ++_q) { \
    float _nv = v[(I)-1][_q] - LR*(ep[_q] - _td[_q]); \
    v[(I)-1][_q] = fminf(fmaxf(_nv, -10.f), 10.f); \
    ep[_q] = _err[_q]; \
  } \
  SCHEDB(0); \
} while(0)

#define FWD(I) do { \
  float _pre[12]; \
  PRED48(v[(I)-1], ((I)-1)*4608, (I)-1, _pre); \
  _Pragma("unroll") \
  for (int _q = 0; _q < 12; ++_q) v[I][_q] = fmaxf(_pre[_q], 0.f); \
  SCHEDB(0); \
} while(0)

__global__ __launch_bounds__(BLOCK) __attribute__((amdgpu_waves_per_eu(2, 2)))
void pcnet_kernel(const float* __restrict__ x, const int* __restrict__ target,
                  const float* __restrict__ W0, const float* __restrict__ b0,
                  const float* __restrict__ Wh, const float* __restrict__ bh,
                  const float* __restrict__ Wout, const float* __restrict__ bout,
                  float* __restrict__ out)
{
    const int t = threadIdx.x;
    const int lane = t & 63;
    const int wv = t >> 6;
    const int n = lane & 15;    // own sample within wave
    const int b = lane >> 4;    // comp sub-block 0..3 (owns comps 16t+4b+q)

    const int bsamp0 = blockIdx.x*64 + wv*16;   // wave's first sample
    const int samp = bsamp0 + n;

    // ======== phase 0: a0 = relu(x@W0^T + b0) via MFMA; x is B-operand ========
    f32x4 acc0[3];
    #pragma unroll
    for (int tm = 0; tm < 3; ++tm) acc0[tm] = (f32x4){0.f, 0.f, 0.f, 0.f};

    const float* xrow = x + (size_t)samp*784;
    for (int ch = 0; ch < 7; ++ch) {
        __syncthreads();
        for (int idx = t; idx < 1344; idx += BLOCK) {
            int st = idx >> 6, LB = idx & 63;
            int tm = st / 7, ksl = st - tm*7;
            int row = 16*tm + (LB & 15);
            int col = ch*112 + ksl*16 + 4*(LB >> 4);
            float4 w4 = *(const float4*)(W0 + row*784 + col);
            *(half4*)(smem + (tm*7+ksl)*512 + LB*8) = PACK4(w4.x, w4.y, w4.z, w4.w);
        }
        __syncthreads();
        #pragma unroll
        for (int ksl = 0; ksl < 7; ++ksl) {
            float4 xv = *(const float4*)(xrow + ch*112 + ksl*16 + 4*b);
            half4 xb = PACK4(xv.x, xv.y, xv.z, xv.w);
            #pragma unroll
            for (int tm = 0; tm < 3; ++tm) {
                half4 A = *(const half4*)(smem + (tm*7+ksl)*512 + lane*8);
                acc0[tm] = MFMA16(A, xb, acc0[tm], 0, 0, 0);
            }
        }
    }

    float v[10][12], a0r[12];
    #pragma unroll
    for (int tm = 0; tm < 3; ++tm) {
        float4 bb = *(const float4*)(b0 + 16*tm + 4*b);
        float bs[4] = {bb.x, bb.y, bb.z, bb.w};
        #pragma unroll
        for (int q = 0; q < 4; ++q) {
            float val = fmaxf(acc0[tm][q] + bs[q], 0.f);
            v[0][tm*4+q] = val;
            a0r[tm*4+q] = val;
        }
    }
    __syncthreads();   // phase-0 reads done before WH staging overwrites

    // ======== stage pred A-frags: 9 layers x 9 subtiles (f16, 8B/lane) ========
    for (int idx = t; idx < 5184; idx += BLOCK) {
        int L = idx / 576;
        int r2 = idx - L*576;
        int st = r2 >> 6, LB = r2 & 63;
        int tm = st / 3, ks = st - tm*3;
        int m  = 16*tm + (LB & 15);
        int k0 = 16*ks + 4*(LB >> 4);
        float4 w4 = *(const float4*)(Wh + L*2304 + m*48 + k0);
        *(half4*)(smem + L*4608 + st*512 + LB*8) = PACK4(w4.x, w4.y, w4.z, w4.w);
    }
    // ======== stage td A-frags: layers I=6..9 (Wh layer 5..8), transposed ======
    for (int idx = t; idx < 2304; idx += BLOCK) {
        int Lt = idx / 576;
        int r2 = idx - Lt*576;
        int st = r2 >> 6, LB = r2 & 63;
        int tm = st / 3, ks = st - tm*3;
        int m  = 16*tm + (LB & 15);
        int k0 = 16*ks + 4*(LB >> 4);
        const float* p = Wh + (Lt+5)*2304 + k0*48 + m;
        *(half4*)(smem + TD_OFF + Lt*4608 + st*512 + LB*8) = PACK4(p[0], p[48], p[96], p[144]);
    }
    for (int idx = t; idx < 432; idx += BLOCK)
        *(float*)(smem + BH_OFF + idx*4) = bh[idx];
    __syncthreads();   // last barrier -- settling loop is barrier-free

    // ======== hoist td frags (layers 1-5), output-layer frags, bias ========
    half4 tdreg[5][9];
    #pragma unroll
    for (int L = 0; L < 5; ++L)
        #pragma unroll
        for (int st = 0; st < 9; ++st) {
            int tm = st / 3, ks = st - tm*3;
            int m  = 16*tm + (lane & 15);
            int k0 = 16*ks + 4*(lane >> 4);
            const float* p = Wh + L*2304 + k0*48 + m;
            tdreg[L][st] = PACK4(p[0], p[48], p[96], p[144]);
        }
    half4 WP[3], WT[3];
    {
        int c = lane & 15;
        #pragma unroll
        for (int ks = 0; ks < 3; ++ks) {
            if (c < 10) {
                float4 w4 = *(const float4*)(Wout + c*48 + 16*ks + 4*(lane >> 4));
                WP[ks] = PACK4(w4.x, w4.y, w4.z, w4.w);
            } else {
                WP[ks] = PACK4(0.f, 0.f, 0.f, 0.f);
            }
        }
        int c0 = 4*(lane >> 4);
        #pragma unroll
        for (int tm = 0; tm < 3; ++tm) {
            int m = 16*tm + (lane & 15);
            float w0 = (c0+0 < 10) ? Wout[(c0+0)*48 + m] : 0.f;
            float w1 = (c0+1 < 10) ? Wout[(c0+1)*48 + m] : 0.f;
            float w2 = (c0+2 < 10) ? Wout[(c0+2)*48 + m] : 0.f;
            float w3 = (c0+3 < 10) ? Wout[(c0+3)*48 + m] : 0.f;
            WT[tm] = PACK4(w0, w1, w2, w3);
        }
    }
    f32x4 bo4;
    #pragma unroll
    for (int q = 0; q < 4; ++q) bo4[q] = (4*b+q < 10) ? bout[4*b+q] : 0.f;
    const int tg = target[samp];

    // ======== forward init layers 1..9 ========
    FWD(1); FWD(2); FWD(3); FWD(4); FWD(5); FWD(6); FWD(7); FWD(8); FWD(9);

    // ======== settling ========
    #pragma unroll 1
    for (int s = 0; s < 20; ++s) {
        float ep[12];
        #pragma unroll
        for (int q = 0; q < 12; ++q) ep[q] = v[0][q] - a0r[q];

        LAYER_STEP(1); LAYER_STEP(2); LAYER_STEP(3); LAYER_STEP(4); LAYER_STEP(5);
        LAYER_STEP(6); LAYER_STEP(7); LAYER_STEP(8); LAYER_STEP(9);

        // ---- output layer (single f16: LR-damped), fully lane-local ----
        {
            half4 B9[3];
            #pragma unroll
            for (int ks = 0; ks < 3; ++ks)
                B9[ks] = PACK4(v[9][ks*4+0], v[9][ks*4+1], v[9][ks*4+2], v[9][ks*4+3]);
            f32x4 accP = bo4;
            #pragma unroll
            for (int ks = 0; ks < 3; ++ks)
                accP = MFMA16(WP[ks], B9[ks], accP, 0, 0, 0);
            int c0 = 4*b;
            float e0 = (c0+0 < 10) ? (((c0+0 == tg) ? 1.f : 0.f) - accP[0]) : 0.f;
            float e1 = (c0+1 < 10) ? (((c0+1 == tg) ? 1.f : 0.f) - accP[1]) : 0.f;
            float e2 = (c0+2 < 10) ? (((c0+2 == tg) ? 1.f : 0.f) - accP[2]) : 0.f;
            float e3 = (c0+3 < 10) ? (((c0+3 == tg) ? 1.f : 0.f) - accP[3]) : 0.f;
            half4 eB = PACK4(e0, e1, e2, e3);   // B[k=class 4b+j][own sample]
            float td10[12];
            #pragma unroll
            for (int tm = 0; tm < 3; ++tm) {
                f32x4 a2 = {0.f, 0.f, 0.f, 0.f};
                a2 = MFMA16(WT[tm], eB, a2, 0, 0, 0);
                #pragma unroll
                for (int q = 0; q < 4; ++q) td10[tm*4+q] = a2[q];
            }
            #pragma unroll
            for (int q = 0; q < 12; ++q) {
                float nv = v[9][q] - LR*(ep[q] - td10[q]);
                v[9][q] = fminf(fmaxf(nv, -10.f), 10.f);
            }
            SCHEDB(0);
        }
    }

    // ======== write V: out[L][sample][comp], comps 16t+4b..+3 contiguous ========
    #pragma unroll
    for (int L2 = 0; L2 < 10; ++L2) {
        #pragma unroll
        for (int tt = 0; tt < 3; ++tt) {
            f32x4 w4 = { v[L2][tt*4+0], v[L2][tt*4+1], v[L2][tt*4+2], v[L2][tt*4+3] };
            *(f32x4*)(out + (size_t)L2*65536*48 + (size_t)samp*48 + tt*16 + 4*b) = w4;
        }
    }
}

extern "C" void kernel_launch(void* const* d_in, const int* in_sizes, int n_in,
                              void* d_out, int out_size, void* d_ws, size_t ws_size,
                              hipStream_t stream) {
    const float* x      = (const float*)d_in[0];
    const int*   target = (const int*)d_in[1];
    const float* W0     = (const float*)d_in[2];
    const float* b0     = (const float*)d_in[3];
    const float* Wh     = (const float*)d_in[4];
    const float* bh     = (const float*)d_in[5];
    const float* Wout   = (const float*)d_in[6];
    const float* bout   = (const float*)d_in[7];
    float* out = (float*)d_out;

    hipFuncSetAttribute((const void*)pcnet_kernel,
                        hipFuncAttributeMaxDynamicSharedMemorySize, LDS_BYTES);

    dim3 grid(65536/64);    // 1024 blocks, 64 samples each
    dim3 block(BLOCK);      // 4 waves x 16 samples; 61632 B LDS -> 2 blocks/CU
    pcnet_kernel<<<grid, block, LDS_BYTES, stream>>>(x, target, W0, b0, Wh, bh, Wout, bout, out);
}

// Round 13
// 573.997 us; speedup vs baseline: 1.0442x; 1.0276x over previous
//
#include <hip/hip_runtime.h>
#include <stdint.h>

typedef __attribute__((ext_vector_type(4))) _Float16 half4;
typedef __attribute__((ext_vector_type(4))) float f32x4;

#define LR 0.1f
#define BLOCK 256
#define MFMA16 __builtin_amdgcn_mfma_f32_16x16x16f16
#define SCHEDB __builtin_amdgcn_sched_barrier

// LDS byte offsets (total 61632 <= 64KB -> 2 blocks/CU, proven round 12)
#define TD_OFF    41472     // td A-frags layers I=6..9: 4 x 4608
#define BH_OFF    59904     // bh f32 9*48 = 1728
#define LDS_BYTES 61632

extern __shared__ unsigned char smem[];

// build half4 from 4 floats, RNE scalar casts (SSA vector inserts, no alloca)
#define PACK4(S0,S1,S2,S3) __extension__({ \
  half4 _b; \
  _b[0] = (_Float16)(S0); _b[1] = (_Float16)(S1); \
  _b[2] = (_Float16)(S2); _b[3] = (_Float16)(S3); \
  _b; })

// td A-frag selector: layers 1-5 from registers, 6-9 from LDS (I is a literal)
#define TDA(I, ST) ((I) <= 5 \
  ? tdreg[(I) <= 5 ? (I)-1 : 0][ST] \
  : *(const half4*)(smem + TD_OFF + ((I) >= 6 ? (I)-6 : 0)*4608 + (ST)*512 + lane*8))

// pred-direction 48x48 matvec, f16 2-term split on values (B), bias from bh LDS.
#define PRED48(SRC, WOFF, LIDX, DST) do { \
  f32x4 _a0 = *(const f32x4*)(smem + BH_OFF + ((LIDX)*48 +  0)*4 + b*16); \
  f32x4 _a1 = *(const f32x4*)(smem + BH_OFF + ((LIDX)*48 + 16)*4 + b*16); \
  f32x4 _a2 = *(const f32x4*)(smem + BH_OFF + ((LIDX)*48 + 32)*4 + b*16); \
  _Pragma("unroll") \
  for (int _ks = 0; _ks < 3; ++_ks) { \
    _Float16 _h0 = (_Float16)SRC[_ks*4+0]; \
    _Float16 _h1 = (_Float16)SRC[_ks*4+1]; \
    _Float16 _h2 = (_Float16)SRC[_ks*4+2]; \
    _Float16 _h3 = (_Float16)SRC[_ks*4+3]; \
    half4 _bh; _bh[0]=_h0; _bh[1]=_h1; _bh[2]=_h2; _bh[3]=_h3; \
    half4 _bl; \
    _bl[0] = (_Float16)(SRC[_ks*4+0] - (float)_h0); \
    _bl[1] = (_Float16)(SRC[_ks*4+1] - (float)_h1); \
    _bl[2] = (_Float16)(SRC[_ks*4+2] - (float)_h2); \
    _bl[3] = (_Float16)(SRC[_ks*4+3] - (float)_h3); \
    half4 _A0 = *(const half4*)(smem + (WOFF) + (0*3+_ks)*512 + lane*8); \
    half4 _A1 = *(const half4*)(smem + (WOFF) + (1*3+_ks)*512 + lane*8); \
    half4 _A2 = *(const half4*)(smem + (WOFF) + (2*3+_ks)*512 + lane*8); \
    _a0 = MFMA16(_A0, _bh, _a0, 0, 0, 0); _a0 = MFMA16(_A0, _bl, _a0, 0, 0, 0); \
    _a1 = MFMA16(_A1, _bh, _a1, 0, 0, 0); _a1 = MFMA16(_A1, _bl, _a1, 0, 0, 0); \
    _a2 = MFMA16(_A2, _bh, _a2, 0, 0, 0); _a2 = MFMA16(_A2, _bl, _a2, 0, 0, 0); \
  } \
  _Pragma("unroll") \
  for (int _q = 0; _q < 4; ++_q) { \
    DST[0+_q] = _a0[_q]; DST[4+_q] = _a1[_q]; DST[8+_q] = _a2[_q]; \
  } \
} while(0)

// td-direction 48x48 matvec, single f16 (LR-damped), no bias. I literal.
#define TD48(SRC, I, DST) do { \
  f32x4 _a0 = {0.f,0.f,0.f,0.f}, _a1 = {0.f,0.f,0.f,0.f}, _a2 = {0.f,0.f,0.f,0.f}; \
  _Pragma("unroll") \
  for (int _ks = 0; _ks < 3; ++_ks) { \
    half4 _bb = PACK4(SRC[_ks*4+0], SRC[_ks*4+1], SRC[_ks*4+2], SRC[_ks*4+3]); \
    half4 _A0 = TDA(I, 0*3+_ks); \
    half4 _A1 = TDA(I, 1*3+_ks); \
    half4 _A2 = TDA(I, 2*3+_ks); \
    _a0 = MFMA16(_A0, _bb, _a0, 0, 0, 0); \
    _a1 = MFMA16(_A1, _bb, _a1, 0, 0, 0); \
    _a2 = MFMA16(_A2, _bb, _a2, 0, 0, 0); \
  } \
  _Pragma("unroll") \
  for (int _q = 0; _q < 4; ++_q) { \
    DST[0+_q] = _a0[_q]; DST[4+_q] = _a1[_q]; DST[8+_q] = _a2[_q]; \
  } \
} while(0)

#define LAYER_STEP(I) do { \
  float _pre[12], _err[12], _me[12], _td[12]; \
  PRED48(v[(I)-1], ((I)-1)*4608, (I)-1, _pre); \
  _Pragma("unroll") \
  for (int _q = 0; _q < 12; ++_q) { \
    float _rl = fmaxf(_pre[_q], 0.f); \
    _err[_q] = v[I][_q] - _rl; \
    _me[_q] = (_pre[_q] > 0.f) ? _err[_q] : 0.f; \
  } \
  TD48(_me, I, _td); \
  _Pragma("unroll") \
  for (int _q = 0; _q < 12; ++_q) { \
    float _nv = v[(I)-1][_q] - LR*(ep[_q] - _td[_q]); \
    v[(I)-1][_q] = fminf(fmaxf(_nv, -10.f), 10.f); \
    ep[_q] = _err[_q]; \
  } \
  SCHEDB(0); \
} while(0)

#define FWD(I) do { \
  float _pre[12]; \
  PRED48(v[(I)-1], ((I)-1)*4608, (I)-1, _pre); \
  _Pragma("unroll") \
  for (int _q = 0; _q < 12; ++_q) v[I][_q] = fmaxf(_pre[_q], 0.f); \
  SCHEDB(0); \
} while(0)

__global__ __launch_bounds__(BLOCK) __attribute__((amdgpu_waves_per_eu(1, 1)))
void pcnet_kernel(const float* __restrict__ x, const int* __restrict__ target,
                  const float* __restrict__ W0, const float* __restrict__ b0,
                  const float* __restrict__ Wh, const float* __restrict__ bh,
                  const float* __restrict__ Wout, const float* __restrict__ bout,
                  float* __restrict__ out)
{
    const int t = threadIdx.x;
    const int lane = t & 63;
    const int wv = t >> 6;
    const int n = lane & 15;    // own sample within wave
    const int b = lane >> 4;    // comp sub-block 0..3 (owns comps 16t+4b+q)

    const int bsamp0 = blockIdx.x*64 + wv*16;   // wave's first sample
    const int samp = bsamp0 + n;

    // ======== phase 0: a0 = relu(x@W0^T + b0) via MFMA; x is B-operand ========
    f32x4 acc0[3];
    #pragma unroll
    for (int tm = 0; tm < 3; ++tm) acc0[tm] = (f32x4){0.f, 0.f, 0.f, 0.f};

    const float* xrow = x + (size_t)samp*784;
    for (int ch = 0; ch < 7; ++ch) {
        __syncthreads();
        for (int idx = t; idx < 1344; idx += BLOCK) {
            int st = idx >> 6, LB = idx & 63;
            int tm = st / 7, ksl = st - tm*7;
            int row = 16*tm + (LB & 15);
            int col = ch*112 + ksl*16 + 4*(LB >> 4);
            float4 w4 = *(const float4*)(W0 + row*784 + col);
            *(half4*)(smem + (tm*7+ksl)*512 + LB*8) = PACK4(w4.x, w4.y, w4.z, w4.w);
        }
        __syncthreads();
        #pragma unroll
        for (int ksl = 0; ksl < 7; ++ksl) {
            float4 xv = *(const float4*)(xrow + ch*112 + ksl*16 + 4*b);
            half4 xb = PACK4(xv.x, xv.y, xv.z, xv.w);
            #pragma unroll
            for (int tm = 0; tm < 3; ++tm) {
                half4 A = *(const half4*)(smem + (tm*7+ksl)*512 + lane*8);
                acc0[tm] = MFMA16(A, xb, acc0[tm], 0, 0, 0);
            }
        }
    }

    float v[10][12], a0r[12];
    #pragma unroll
    for (int tm = 0; tm < 3; ++tm) {
        float4 bb = *(const float4*)(b0 + 16*tm + 4*b);
        float bs[4] = {bb.x, bb.y, bb.z, bb.w};
        #pragma unroll
        for (int q = 0; q < 4; ++q) {
            float val = fmaxf(acc0[tm][q] + bs[q], 0.f);
            v[0][tm*4+q] = val;
            a0r[tm*4+q] = val;
        }
    }
    __syncthreads();   // phase-0 reads done before WH staging overwrites

    // ======== stage pred A-frags: 9 layers x 9 subtiles (f16, 8B/lane) ========
    for (int idx = t; idx < 5184; idx += BLOCK) {
        int L = idx / 576;
        int r2 = idx - L*576;
        int st = r2 >> 6, LB = r2 & 63;
        int tm = st / 3, ks = st - tm*3;
        int m  = 16*tm + (LB & 15);
        int k0 = 16*ks + 4*(LB >> 4);
        float4 w4 = *(const float4*)(Wh + L*2304 + m*48 + k0);
        *(half4*)(smem + L*4608 + st*512 + LB*8) = PACK4(w4.x, w4.y, w4.z, w4.w);
    }
    // ======== stage td A-frags: layers I=6..9 (Wh layer 5..8), transposed ======
    for (int idx = t; idx < 2304; idx += BLOCK) {
        int Lt = idx / 576;
        int r2 = idx - Lt*576;
        int st = r2 >> 6, LB = r2 & 63;
        int tm = st / 3, ks = st - tm*3;
        int m  = 16*tm + (LB & 15);
        int k0 = 16*ks + 4*(LB >> 4);
        const float* p = Wh + (Lt+5)*2304 + k0*48 + m;
        *(half4*)(smem + TD_OFF + Lt*4608 + st*512 + LB*8) = PACK4(p[0], p[48], p[96], p[144]);
    }
    for (int idx = t; idx < 432; idx += BLOCK)
        *(float*)(smem + BH_OFF + idx*4) = bh[idx];
    __syncthreads();   // last barrier -- settling loop is barrier-free

    // ======== hoist td frags (layers 1-5), output-layer frags, bias ========
    half4 tdreg[5][9];
    #pragma unroll
    for (int L = 0; L < 5; ++L)
        #pragma unroll
        for (int st = 0; st < 9; ++st) {
            int tm = st / 3, ks = st - tm*3;
            int m  = 16*tm + (lane & 15);
            int k0 = 16*ks + 4*(lane >> 4);
            const float* p = Wh + L*2304 + k0*48 + m;
            tdreg[L][st] = PACK4(p[0], p[48], p[96], p[144]);
        }
    half4 WP[3], WT[3];
    {
        int c = lane & 15;
        #pragma unroll
        for (int ks = 0; ks < 3; ++ks) {
            if (c < 10) {
                float4 w4 = *(const float4*)(Wout + c*48 + 16*ks + 4*(lane >> 4));
                WP[ks] = PACK4(w4.x, w4.y, w4.z, w4.w);
            } else {
                WP[ks] = PACK4(0.f, 0.f, 0.f, 0.f);
            }
        }
        int c0 = 4*(lane >> 4);
        #pragma unroll
        for (int tm = 0; tm < 3; ++tm) {
            int m = 16*tm + (lane & 15);
            float w0 = (c0+0 < 10) ? Wout[(c0+0)*48 + m] : 0.f;
            float w1 = (c0+1 < 10) ? Wout[(c0+1)*48 + m] : 0.f;
            float w2 = (c0+2 < 10) ? Wout[(c0+2)*48 + m] : 0.f;
            float w3 = (c0+3 < 10) ? Wout[(c0+3)*48 + m] : 0.f;
            WT[tm] = PACK4(w0, w1, w2, w3);
        }
    }
    f32x4 bo4;
    #pragma unroll
    for (int q = 0; q < 4; ++q) bo4[q] = (4*b+q < 10) ? bout[4*b+q] : 0.f;
    const int tg = target[samp];

    // ======== forward init layers 1..9 ========
    FWD(1); FWD(2); FWD(3); FWD(4); FWD(5); FWD(6); FWD(7); FWD(8); FWD(9);

    // ======== settling ========
    #pragma unroll 1
    for (int s = 0; s < 20; ++s) {
        float ep[12];
        #pragma unroll
        for (int q = 0; q < 12; ++q) ep[q] = v[0][q] - a0r[q];

        LAYER_STEP(1); LAYER_STEP(2); LAYER_STEP(3); LAYER_STEP(4); LAYER_STEP(5);
        LAYER_STEP(6); LAYER_STEP(7); LAYER_STEP(8); LAYER_STEP(9);

        // ---- output layer (single f16: LR-damped), fully lane-local ----
        {
            half4 B9[3];
            #pragma unroll
            for (int ks = 0; ks < 3; ++ks)
                B9[ks] = PACK4(v[9][ks*4+0], v[9][ks*4+1], v[9][ks*4+2], v[9][ks*4+3]);
            f32x4 accP = bo4;
            #pragma unroll
            for (int ks = 0; ks < 3; ++ks)
                accP = MFMA16(WP[ks], B9[ks], accP, 0, 0, 0);
            int c0 = 4*b;
            float e0 = (c0+0 < 10) ? (((c0+0 == tg) ? 1.f : 0.f) - accP[0]) : 0.f;
            float e1 = (c0+1 < 10) ? (((c0+1 == tg) ? 1.f : 0.f) - accP[1]) : 0.f;
            float e2 = (c0+2 < 10) ? (((c0+2 == tg) ? 1.f : 0.f) - accP[2]) : 0.f;
            float e3 = (c0+3 < 10) ? (((c0+3 == tg) ? 1.f : 0.f) - accP[3]) : 0.f;
            half4 eB = PACK4(e0, e1, e2, e3);   // B[k=class 4b+j][own sample]
            float td10[12];
            #pragma unroll
            for (int tm = 0; tm < 3; ++tm) {
                f32x4 a2 = {0.f, 0.f, 0.f, 0.f};
                a2 = MFMA16(WT[tm], eB, a2, 0, 0, 0);
                #pragma unroll
                for (int q = 0; q < 4; ++q) td10[tm*4+q] = a2[q];
            }
            #pragma unroll
            for (int q = 0; q < 12; ++q) {
                float nv = v[9][q] - LR*(ep[q] - td10[q]);
                v[9][q] = fminf(fmaxf(nv, -10.f), 10.f);
            }
            SCHEDB(0);
        }
    }

    // ======== write V: out[L][sample][comp], comps 16t+4b..+3 contiguous ========
    #pragma unroll
    for (int L2 = 0; L2 < 10; ++L2) {
        #pragma unroll
        for (int tt = 0; tt < 3; ++tt) {
            f32x4 w4 = { v[L2][tt*4+0], v[L2][tt*4+1], v[L2][tt*4+2], v[L2][tt*4+3] };
            *(f32x4*)(out + (size_t)L2*65536*48 + (size_t)samp*48 + tt*16 + 4*b) = w4;
        }
    }
}

extern "C" void kernel_launch(void* const* d_in, const int* in_sizes, int n_in,
                              void* d_out, int out_size, void* d_ws, size_t ws_size,
                              hipStream_t stream) {
    const float* x      = (const float*)d_in[0];
    const int*   target = (const int*)d_in[1];
    const float* W0     = (const float*)d_in[2];
    const float* b0     = (const float*)d_in[3];
    const float* Wh     = (const float*)d_in[4];
    const float* bh     = (const float*)d_in[5];
    const float* Wout   = (const float*)d_in[6];
    const float* bout   = (const float*)d_in[7];
    float* out = (float*)d_out;

    hipFuncSetAttribute((const void*)pcnet_kernel,
                        hipFuncAttributeMaxDynamicSharedMemorySize, LDS_BYTES);

    dim3 grid(65536/64);    // 1024 blocks, 64 samples each
    dim3 block(BLOCK);      // 4 waves x 16 samples; 61632 B LDS -> 2 blocks/CU
    pcnet_kernel<<<grid, block, LDS_BYTES, stream>>>(x, target, W0, b0, Wh, bh, Wout, bout, out);
}